// Round 1
// baseline (1192.965 us; speedup 1.0000x reference)
//
#include <hip/hip_runtime.h>

// EdgeWeightPredictor: 2-layer GCN (sym-norm, self-loops) + edge MLP.
// N=100000 nodes (IN_CH=6), E=1600000 edges (EDGE_FEAT=8).
// All fp32. edge_index is int32 (JAX x64 disabled).

constexpr int TPB = 256;

// ---- degree count: deg[dst] += 1 ------------------------------------------
__global__ void k_deg(const int* __restrict__ dst, float* __restrict__ deg, int E) {
    int i = blockIdx.x * blockDim.x + threadIdx.x;
    if (i < E) unsafeAtomicAdd(&deg[dst[i]], 1.0f);
}

// ---- deg -> rsqrt(deg+1) in place -----------------------------------------
__global__ void k_dinv(float* __restrict__ deg, int N) {
    int i = blockIdx.x * blockDim.x + threadIdx.x;
    if (i < N) deg[i] = rsqrtf(deg[i] + 1.0f);
}

// ---- hlin1 = x @ W1   (thread per (node, outch)) --------------------------
__global__ void k_lin1(const float* __restrict__ x, const float* __restrict__ W1,
                       float* __restrict__ hlin1, int N) {
    int gid = blockIdx.x * blockDim.x + threadIdx.x;
    if (gid >= N * 32) return;
    int n = gid >> 5, oc = gid & 31;
    const float* xr = x + (size_t)n * 6;
    float s = 0.f;
#pragma unroll
    for (int k = 0; k < 6; ++k) s = fmaf(xr[k], W1[k * 32 + oc], s);
    hlin1[gid] = s;
}

// ---- scatter-add: agg[dst] += h[src] * dinv[src]*dinv[dst] ----------------
// C channels; C/4 threads per edge, float4 per thread.
template <int C>
__global__ void k_agg(const int* __restrict__ src, const int* __restrict__ dst,
                      const float* __restrict__ dinv, const float* __restrict__ h,
                      float* __restrict__ agg, int E) {
    constexpr int G = C / 4;
    int gid = blockIdx.x * blockDim.x + threadIdx.x;
    if (gid >= E * G) return;
    int e = gid / G, g = gid % G;
    int s = src[e], d = dst[e];
    float norm = dinv[s] * dinv[d];
    float4 v = *reinterpret_cast<const float4*>(h + (size_t)s * C + g * 4);
    float* ap = agg + (size_t)d * C + g * 4;
    unsafeAtomicAdd(ap + 0, v.x * norm);
    unsafeAtomicAdd(ap + 1, v.y * norm);
    unsafeAtomicAdd(ap + 2, v.z * norm);
    unsafeAtomicAdd(ap + 3, v.w * norm);
}

// ---- layer-1 finalize fused with @W2: hlin2[n][j] -------------------------
// h1out[c] = relu(agg1[n][c] + hlin1[n][c]*dinv^2 + b1[c])
// hlin2[n][j] = sum_c h1out[c] * W2[c][j]     (thread per (node, j), j<16)
__global__ void k_fin1(const float* __restrict__ agg1, const float* __restrict__ hlin1,
                       const float* __restrict__ dinv, const float* __restrict__ b1,
                       const float* __restrict__ W2, float* __restrict__ hlin2, int N) {
    int gid = blockIdx.x * blockDim.x + threadIdx.x;
    if (gid >= N * 16) return;
    int n = gid >> 4, j = gid & 15;
    float di = dinv[n];
    float d2 = di * di;
    const float* ag = agg1 + (size_t)n * 32;
    const float* hl = hlin1 + (size_t)n * 32;
    float acc = 0.f;
#pragma unroll
    for (int c = 0; c < 32; ++c) {
        float hv = fmaf(hl[c], d2, ag[c]) + b1[c];
        hv = fmaxf(hv, 0.f);
        acc = fmaf(hv, W2[c * 16 + j], acc);
    }
    hlin2[gid] = acc;
}

// ---- layer-2 finalize: h2 = relu(agg2 + hlin2*dinv^2 + b2) ----------------
__global__ void k_fin2(const float* __restrict__ agg2, const float* __restrict__ hlin2,
                       const float* __restrict__ dinv, const float* __restrict__ b2,
                       float* __restrict__ h2, int N) {
    int gid = blockIdx.x * blockDim.x + threadIdx.x;
    if (gid >= N * 16) return;
    int n = gid >> 4, c = gid & 15;
    float di = dinv[n];
    float v = fmaf(hlin2[gid], di * di, agg2[gid]) + b2[c];
    h2[gid] = fmaxf(v, 0.f);
}

// ---- edge MLP: out[e] = relu([h2[s],h2[d],ea[e]] @ W3 + b3) @ W4 + b4 -----
__global__ void __launch_bounds__(TPB) k_edge(
    const int* __restrict__ src, const int* __restrict__ dst,
    const float* __restrict__ h2, const float* __restrict__ eattr,
    const float* __restrict__ W3, const float* __restrict__ b3,
    const float* __restrict__ W4, const float* __restrict__ b4,
    float* __restrict__ out, int E) {
    __shared__ float sW3[40 * 32];
    __shared__ float sb3[32];
    __shared__ float sW4[32];
    __shared__ float sb4;
    for (int i = threadIdx.x; i < 40 * 32; i += TPB) sW3[i] = W3[i];
    if (threadIdx.x < 32) {
        sb3[threadIdx.x] = b3[threadIdx.x];
        sW4[threadIdx.x] = W4[threadIdx.x];
    }
    if (threadIdx.x == 0) sb4 = b4[0];
    __syncthreads();

    int e = blockIdx.x * TPB + threadIdx.x;
    if (e >= E) return;
    int s = src[e], d = dst[e];

    float in[40];
    {
        const float4* hs = reinterpret_cast<const float4*>(h2 + (size_t)s * 16);
        const float4* hd = reinterpret_cast<const float4*>(h2 + (size_t)d * 16);
        const float4* ea = reinterpret_cast<const float4*>(eattr + (size_t)e * 8);
#pragma unroll
        for (int q = 0; q < 4; ++q) {
            float4 t = hs[q];
            in[q * 4 + 0] = t.x; in[q * 4 + 1] = t.y; in[q * 4 + 2] = t.z; in[q * 4 + 3] = t.w;
        }
#pragma unroll
        for (int q = 0; q < 4; ++q) {
            float4 t = hd[q];
            in[16 + q * 4 + 0] = t.x; in[16 + q * 4 + 1] = t.y; in[16 + q * 4 + 2] = t.z; in[16 + q * 4 + 3] = t.w;
        }
#pragma unroll
        for (int q = 0; q < 2; ++q) {
            float4 t = ea[q];
            in[32 + q * 4 + 0] = t.x; in[32 + q * 4 + 1] = t.y; in[32 + q * 4 + 2] = t.z; in[32 + q * 4 + 3] = t.w;
        }
    }

    const float4* sW3v = reinterpret_cast<const float4*>(sW3);  // [40][8]
    float acc = sb4;
#pragma unroll
    for (int jq = 0; jq < 8; ++jq) {
        float z0 = sb3[jq * 4 + 0], z1 = sb3[jq * 4 + 1],
              z2 = sb3[jq * 4 + 2], z3 = sb3[jq * 4 + 3];
#pragma unroll
        for (int k = 0; k < 40; ++k) {
            float4 wv = sW3v[k * 8 + jq];  // broadcast LDS read (uniform addr)
            float a = in[k];
            z0 = fmaf(a, wv.x, z0);
            z1 = fmaf(a, wv.y, z1);
            z2 = fmaf(a, wv.z, z2);
            z3 = fmaf(a, wv.w, z3);
        }
        acc = fmaf(fmaxf(z0, 0.f), sW4[jq * 4 + 0], acc);
        acc = fmaf(fmaxf(z1, 0.f), sW4[jq * 4 + 1], acc);
        acc = fmaf(fmaxf(z2, 0.f), sW4[jq * 4 + 2], acc);
        acc = fmaf(fmaxf(z3, 0.f), sW4[jq * 4 + 3], acc);
    }
    out[e] = acc;
}

extern "C" void kernel_launch(void* const* d_in, const int* in_sizes, int n_in,
                              void* d_out, int out_size, void* d_ws, size_t ws_size,
                              hipStream_t stream) {
    const float* x     = (const float*)d_in[0];
    const int*   ei    = (const int*)d_in[1];
    const float* eattr = (const float*)d_in[2];
    const float* W1 = (const float*)d_in[3];
    const float* b1 = (const float*)d_in[4];
    const float* W2 = (const float*)d_in[5];
    const float* b2 = (const float*)d_in[6];
    const float* W3 = (const float*)d_in[7];
    const float* b3 = (const float*)d_in[8];
    const float* W4 = (const float*)d_in[9];
    const float* b4 = (const float*)d_in[10];
    float* out = (float*)d_out;

    const int N = in_sizes[0] / 6;     // 100000
    const int E = in_sizes[2] / 8;     // 1600000
    const int* src = ei;
    const int* dst = ei + E;

    // workspace layout (floats)
    float* w = (float*)d_ws;
    float* dinv  = w;                        // N   (deg, then rsqrt in place)
    float* hlin1 = w + (size_t)N;            // N*32
    float* agg1  = w + (size_t)N * 33;       // N*32
    float* hlin2 = w + (size_t)N * 65;       // N*16
    float* agg2  = w + (size_t)N * 81;       // N*16
    float* h2    = w + (size_t)N * 97;       // N*16
    // total 113*N floats = 45.2 MB

    hipMemsetAsync(dinv, 0, (size_t)N * sizeof(float), stream);
    hipMemsetAsync(agg1, 0, (size_t)N * 32 * sizeof(float), stream);
    hipMemsetAsync(agg2, 0, (size_t)N * 16 * sizeof(float), stream);

    k_deg<<<(E + TPB - 1) / TPB, TPB, 0, stream>>>(dst, dinv, E);
    k_dinv<<<(N + TPB - 1) / TPB, TPB, 0, stream>>>(dinv, N);
    k_lin1<<<(N * 32 + TPB - 1) / TPB, TPB, 0, stream>>>(x, W1, hlin1, N);
    k_agg<32><<<(E * 8 + TPB - 1) / TPB, TPB, 0, stream>>>(src, dst, dinv, hlin1, agg1, E);
    k_fin1<<<(N * 16 + TPB - 1) / TPB, TPB, 0, stream>>>(agg1, hlin1, dinv, b1, W2, hlin2, N);
    k_agg<16><<<(E * 4 + TPB - 1) / TPB, TPB, 0, stream>>>(src, dst, dinv, hlin2, agg2, E);
    k_fin2<<<(N * 16 + TPB - 1) / TPB, TPB, 0, stream>>>(agg2, hlin2, dinv, b2, h2, N);
    k_edge<<<(E + TPB - 1) / TPB, TPB, 0, stream>>>(src, dst, h2, eattr, W3, b3, W4, b4, out, E);
}

// Round 2
// 416.925 us; speedup vs baseline: 2.8613x; 2.8613x over previous
//
#include <hip/hip_runtime.h>

// EdgeWeightPredictor: 2-layer GCN (sym-norm, self-loops) + edge MLP.
// N=100000 nodes (IN_CH=6), E=1600000 edges (EDGE_FEAT=8). All fp32.
// Round 2: replace float atomic scatters (1.2 GB write-through, 974 us)
// with per-launch CSR build (int atomics) + gather-style aggregation.

constexpr int TPB = 256;

// ---- degree histogram: deg[dst]++ -----------------------------------------
__global__ void k_hist(const int* __restrict__ dst, unsigned* __restrict__ deg, int E) {
    int i = blockIdx.x * blockDim.x + threadIdx.x;
    if (i < E) atomicAdd(&deg[dst[i]], 1u);
}

// ---- scan pass 1: per-block sums of deg -----------------------------------
__global__ void k_scan1(const unsigned* __restrict__ deg, unsigned* __restrict__ bsum, int N) {
    __shared__ unsigned s[TPB];
    int tid = threadIdx.x;
    int i = blockIdx.x * TPB + tid;
    unsigned v = (i < N) ? deg[i] : 0u;
    s[tid] = v;
    __syncthreads();
    for (int ofs = TPB / 2; ofs > 0; ofs >>= 1) {
        if (tid < ofs) s[tid] += s[tid + ofs];
        __syncthreads();
    }
    if (tid == 0) bsum[blockIdx.x] = s[0];
}

// ---- scan pass 2: exclusive scan of block sums (1 block, 512 thr) ---------
__global__ void k_scan2(unsigned* __restrict__ bsum, int nb) {
    __shared__ unsigned s[512];
    int tid = threadIdx.x;
    unsigned v = (tid < nb) ? bsum[tid] : 0u;
    s[tid] = v;
    __syncthreads();
    for (int ofs = 1; ofs < 512; ofs <<= 1) {
        unsigned t = (tid >= ofs) ? s[tid - ofs] : 0u;
        __syncthreads();
        s[tid] += t;
        __syncthreads();
    }
    if (tid < nb) bsum[tid] = s[tid] - v;  // exclusive
}

// ---- scan pass 3: rowptr/wc/dinv ------------------------------------------
__global__ void k_scan3(const unsigned* __restrict__ deg, const unsigned* __restrict__ bsum,
                        unsigned* __restrict__ rowptr, unsigned* __restrict__ wc,
                        float* __restrict__ dinv, int N) {
    __shared__ unsigned s[TPB];
    int tid = threadIdx.x;
    int i = blockIdx.x * TPB + tid;
    unsigned v = (i < N) ? deg[i] : 0u;
    s[tid] = v;
    __syncthreads();
    for (int ofs = 1; ofs < TPB; ofs <<= 1) {
        unsigned t = (tid >= ofs) ? s[tid - ofs] : 0u;
        __syncthreads();
        s[tid] += t;
        __syncthreads();
    }
    unsigned excl = bsum[blockIdx.x] + s[tid] - v;
    if (i < N) {
        rowptr[i] = excl;
        wc[i] = excl;
        dinv[i] = rsqrtf((float)v + 1.0f);
        if (i == N - 1) rowptr[N] = excl + v;
    }
}

// ---- CSR placement: csr_src[pos++] = src ----------------------------------
__global__ void k_place(const int* __restrict__ src, const int* __restrict__ dst,
                        unsigned* __restrict__ wc, int* __restrict__ csr_src, int E) {
    int e = blockIdx.x * blockDim.x + threadIdx.x;
    if (e < E) {
        unsigned pos = atomicAdd(&wc[dst[e]], 1u);
        csr_src[pos] = src[e];
    }
}

// ---- hs1 = (x @ W1) * dinv[n]   (thread per (node, outch)) ----------------
__global__ void k_lin1(const float* __restrict__ x, const float* __restrict__ W1,
                       const float* __restrict__ dinv, float* __restrict__ hs1, int N) {
    int gid = blockIdx.x * blockDim.x + threadIdx.x;
    if (gid >= N * 32) return;
    int n = gid >> 5, oc = gid & 31;
    const float* xr = x + (size_t)n * 6;
    float s = 0.f;
#pragma unroll
    for (int k = 0; k < 6; ++k) s = fmaf(xr[k], W1[k * 32 + oc], s);
    hs1[gid] = s * dinv[n];
}

// ---- gather aggregation: out[n] = relu(dinv[n]*(self + sum_in hs[src]) + b)
// C channels, C/4 lanes per node, float4 per lane. csr_src reads broadcast.
template <int C>
__global__ void k_gagg(const unsigned* __restrict__ rowptr, const int* __restrict__ csr_src,
                       const float* __restrict__ dinv, const float* __restrict__ hs,
                       const float* __restrict__ b, float* __restrict__ outp, int N) {
    constexpr int G = C / 4;
    int gid = blockIdx.x * blockDim.x + threadIdx.x;
    int n = gid / G, g = gid % G;
    if (n >= N) return;
    unsigned beg = rowptr[n], end = rowptr[n + 1];
    const float4* hsv = reinterpret_cast<const float4*>(hs);
    float4 acc = hsv[(size_t)n * G + g];  // self-loop term (hs = h*dinv)
    for (unsigned j = beg; j < end; ++j) {
        int s = csr_src[j];
        float4 v = hsv[(size_t)s * G + g];
        acc.x += v.x; acc.y += v.y; acc.z += v.z; acc.w += v.w;
    }
    float di = dinv[n];
    float4 bb = reinterpret_cast<const float4*>(b)[g];
    float4 r;
    r.x = fmaxf(fmaf(acc.x, di, bb.x), 0.f);
    r.y = fmaxf(fmaf(acc.y, di, bb.y), 0.f);
    r.z = fmaxf(fmaf(acc.z, di, bb.z), 0.f);
    r.w = fmaxf(fmaf(acc.w, di, bb.w), 0.f);
    reinterpret_cast<float4*>(outp)[(size_t)n * G + g] = r;
}

// ---- hs2 = (h1out @ W2) * dinv   (thread per (node, j), j<16) -------------
__global__ void k_lin2(const float* __restrict__ h1out, const float* __restrict__ W2,
                       const float* __restrict__ dinv, float* __restrict__ hs2, int N) {
    int gid = blockIdx.x * blockDim.x + threadIdx.x;
    if (gid >= N * 16) return;
    int n = gid >> 4, j = gid & 15;
    const float* hr = h1out + (size_t)n * 32;
    float acc = 0.f;
#pragma unroll
    for (int c = 0; c < 32; ++c) acc = fmaf(hr[c], W2[c * 16 + j], acc);
    hs2[gid] = acc * dinv[n];
}

// ---- edge MLP: out[e] = relu([h2[s],h2[d],ea[e]] @ W3 + b3) @ W4 + b4 -----
__global__ void __launch_bounds__(TPB) k_edge(
    const int* __restrict__ src, const int* __restrict__ dst,
    const float* __restrict__ h2, const float* __restrict__ eattr,
    const float* __restrict__ W3, const float* __restrict__ b3,
    const float* __restrict__ W4, const float* __restrict__ b4,
    float* __restrict__ out, int E) {
    __shared__ float sW3[40 * 32];
    __shared__ float sb3[32];
    __shared__ float sW4[32];
    __shared__ float sb4;
    for (int i = threadIdx.x; i < 40 * 32; i += TPB) sW3[i] = W3[i];
    if (threadIdx.x < 32) {
        sb3[threadIdx.x] = b3[threadIdx.x];
        sW4[threadIdx.x] = W4[threadIdx.x];
    }
    if (threadIdx.x == 0) sb4 = b4[0];
    __syncthreads();

    int e = blockIdx.x * TPB + threadIdx.x;
    if (e >= E) return;
    int s = src[e], d = dst[e];

    float in[40];
    {
        const float4* hs = reinterpret_cast<const float4*>(h2 + (size_t)s * 16);
        const float4* hd = reinterpret_cast<const float4*>(h2 + (size_t)d * 16);
        const float4* ea = reinterpret_cast<const float4*>(eattr + (size_t)e * 8);
#pragma unroll
        for (int q = 0; q < 4; ++q) {
            float4 t = hs[q];
            in[q * 4 + 0] = t.x; in[q * 4 + 1] = t.y; in[q * 4 + 2] = t.z; in[q * 4 + 3] = t.w;
        }
#pragma unroll
        for (int q = 0; q < 4; ++q) {
            float4 t = hd[q];
            in[16 + q * 4 + 0] = t.x; in[16 + q * 4 + 1] = t.y; in[16 + q * 4 + 2] = t.z; in[16 + q * 4 + 3] = t.w;
        }
#pragma unroll
        for (int q = 0; q < 2; ++q) {
            float4 t = ea[q];
            in[32 + q * 4 + 0] = t.x; in[32 + q * 4 + 1] = t.y; in[32 + q * 4 + 2] = t.z; in[32 + q * 4 + 3] = t.w;
        }
    }

    const float4* sW3v = reinterpret_cast<const float4*>(sW3);  // [40][8]
    float acc = sb4;
#pragma unroll
    for (int jq = 0; jq < 8; ++jq) {
        float z0 = sb3[jq * 4 + 0], z1 = sb3[jq * 4 + 1],
              z2 = sb3[jq * 4 + 2], z3 = sb3[jq * 4 + 3];
#pragma unroll
        for (int k = 0; k < 40; ++k) {
            float4 wv = sW3v[k * 8 + jq];  // broadcast LDS read (uniform addr)
            float a = in[k];
            z0 = fmaf(a, wv.x, z0);
            z1 = fmaf(a, wv.y, z1);
            z2 = fmaf(a, wv.z, z2);
            z3 = fmaf(a, wv.w, z3);
        }
        acc = fmaf(fmaxf(z0, 0.f), sW4[jq * 4 + 0], acc);
        acc = fmaf(fmaxf(z1, 0.f), sW4[jq * 4 + 1], acc);
        acc = fmaf(fmaxf(z2, 0.f), sW4[jq * 4 + 2], acc);
        acc = fmaf(fmaxf(z3, 0.f), sW4[jq * 4 + 3], acc);
    }
    out[e] = acc;
}

extern "C" void kernel_launch(void* const* d_in, const int* in_sizes, int n_in,
                              void* d_out, int out_size, void* d_ws, size_t ws_size,
                              hipStream_t stream) {
    const float* x     = (const float*)d_in[0];
    const int*   ei    = (const int*)d_in[1];
    const float* eattr = (const float*)d_in[2];
    const float* W1 = (const float*)d_in[3];
    const float* b1 = (const float*)d_in[4];
    const float* W2 = (const float*)d_in[5];
    const float* b2 = (const float*)d_in[6];
    const float* W3 = (const float*)d_in[7];
    const float* b3 = (const float*)d_in[8];
    const float* W4 = (const float*)d_in[9];
    const float* b4 = (const float*)d_in[10];
    float* out = (float*)d_out;

    const int N = in_sizes[0] / 6;     // 100000
    const int E = in_sizes[2] / 8;     // 1600000
    const int nb = (N + TPB - 1) / TPB;  // 391 scan blocks (must be <= 512)
    const int* src = ei;
    const int* dst = ei + E;

    // workspace layout (4-byte units, regions 16B-aligned)
    char* wsb = (char*)d_ws;
    size_t off = 0;
    auto alloc4 = [&](size_t elems) {
        void* p = wsb + off;
        off += ((elems * 4 + 15) & ~(size_t)15);
        return p;
    };
    unsigned* deg     = (unsigned*)alloc4(N);
    unsigned* rowptr  = (unsigned*)alloc4(N + 1);
    unsigned* wc      = (unsigned*)alloc4(N);
    float*    dinv    = (float*)alloc4(N);
    unsigned* bsum    = (unsigned*)alloc4(512);
    int*      csr_src = (int*)alloc4(E);
    float*    hs1     = (float*)alloc4((size_t)N * 32);  // reused: hs2 / h2
    float*    h1out   = (float*)alloc4((size_t)N * 32);
    float*    hs2 = hs1;               // hs1 dead after k_gagg<32>
    float*    h2  = hs1 + (size_t)N * 16;
    // total ~34 MB

    hipMemsetAsync(deg, 0, (size_t)N * sizeof(unsigned), stream);

    // CSR build (int atomics only)
    k_hist <<<(E + TPB - 1) / TPB, TPB, 0, stream>>>(dst, deg, E);
    k_scan1<<<nb, TPB, 0, stream>>>(deg, bsum, N);
    k_scan2<<<1, 512, 0, stream>>>(bsum, nb);
    k_scan3<<<nb, TPB, 0, stream>>>(deg, bsum, rowptr, wc, dinv, N);
    k_place<<<(E + TPB - 1) / TPB, TPB, 0, stream>>>(src, dst, wc, csr_src, E);

    // GCN layer 1
    k_lin1<<<(N * 32 + TPB - 1) / TPB, TPB, 0, stream>>>(x, W1, dinv, hs1, N);
    k_gagg<32><<<((size_t)N * 8 + TPB - 1) / TPB, TPB, 0, stream>>>(rowptr, csr_src, dinv, hs1, b1, h1out, N);

    // GCN layer 2
    k_lin2<<<(N * 16 + TPB - 1) / TPB, TPB, 0, stream>>>(h1out, W2, dinv, hs2, N);
    k_gagg<16><<<((size_t)N * 4 + TPB - 1) / TPB, TPB, 0, stream>>>(rowptr, csr_src, dinv, hs2, b2, h2, N);

    // edge MLP
    k_edge<<<(E + TPB - 1) / TPB, TPB, 0, stream>>>(src, dst, h2, eattr, W3, b3, W4, b4, out, E);
}

// Round 3
// 308.654 us; speedup vs baseline: 3.8651x; 1.3508x over previous
//
#include <hip/hip_runtime.h>

// EdgeWeightPredictor: 2-layer GCN (sym-norm, self-loops) + edge MLP.
// N=100000 nodes (IN_CH=6), E=1600000 edges (EDGE_FEAT=8). All fp32.
// Round 3: k_place's scattered 4B stores caused 16x write amplification
// (105 MB, 137 us). Replace with 2-level bucket sort (dst>>8 buckets) so
// every csr line is written by one block, temporally clustered.
// Also: k_edge weights via uniform global reads (s_load) instead of LDS.

constexpr int TPB = 256;
constexpr int NB = 256;         // level-1 blocks
constexpr int BSH = 8;          // 256 nodes per bucket
constexpr int MAXB = 1024;      // max buckets supported (N <= 262144)

// ---- degree histogram: deg[dst]++ -----------------------------------------
__global__ void k_hist(const int* __restrict__ dst, unsigned* __restrict__ deg, int E) {
    int i = blockIdx.x * blockDim.x + threadIdx.x;
    if (i < E) atomicAdd(&deg[dst[i]], 1u);
}

// ---- scan pass 1: per-block sums ------------------------------------------
__global__ void k_scan1(const unsigned* __restrict__ v_in, unsigned* __restrict__ bsum, int M) {
    __shared__ unsigned s[TPB];
    int tid = threadIdx.x;
    int i = blockIdx.x * TPB + tid;
    unsigned v = (i < M) ? v_in[i] : 0u;
    s[tid] = v;
    __syncthreads();
    for (int ofs = TPB / 2; ofs > 0; ofs >>= 1) {
        if (tid < ofs) s[tid] += s[tid + ofs];
        __syncthreads();
    }
    if (tid == 0) bsum[blockIdx.x] = s[0];
}

// transposed read: element m (bucket-major) = histG[(m%NB)*B + m/NB]
__global__ void k_scan1t(const unsigned* __restrict__ histG, unsigned* __restrict__ bsum,
                         int M, int B) {
    __shared__ unsigned s[TPB];
    int tid = threadIdx.x;
    int i = blockIdx.x * TPB + tid;
    unsigned v = (i < M) ? histG[(i % NB) * B + (i / NB)] : 0u;
    s[tid] = v;
    __syncthreads();
    for (int ofs = TPB / 2; ofs > 0; ofs >>= 1) {
        if (tid < ofs) s[tid] += s[tid + ofs];
        __syncthreads();
    }
    if (tid == 0) bsum[blockIdx.x] = s[0];
}

// ---- scan pass 2: exclusive scan of block sums (1 block, 512 thr) ---------
__global__ void k_scan2(unsigned* __restrict__ bsum, int nb) {
    __shared__ unsigned s[512];
    int tid = threadIdx.x;
    unsigned v = (tid < nb) ? bsum[tid] : 0u;
    s[tid] = v;
    __syncthreads();
    for (int ofs = 1; ofs < 512; ofs <<= 1) {
        unsigned t = (tid >= ofs) ? s[tid - ofs] : 0u;
        __syncthreads();
        s[tid] += t;
        __syncthreads();
    }
    if (tid < nb) bsum[tid] = s[tid] - v;  // exclusive
}

// ---- scan pass 3 (deg): rowptr + dinv -------------------------------------
__global__ void k_scan3(const unsigned* __restrict__ deg, const unsigned* __restrict__ bsum,
                        unsigned* __restrict__ rowptr, float* __restrict__ dinv, int N) {
    __shared__ unsigned s[TPB];
    int tid = threadIdx.x;
    int i = blockIdx.x * TPB + tid;
    unsigned v = (i < N) ? deg[i] : 0u;
    s[tid] = v;
    __syncthreads();
    for (int ofs = 1; ofs < TPB; ofs <<= 1) {
        unsigned t = (tid >= ofs) ? s[tid - ofs] : 0u;
        __syncthreads();
        s[tid] += t;
        __syncthreads();
    }
    unsigned excl = bsum[blockIdx.x] + s[tid] - v;
    if (i < N) {
        rowptr[i] = excl;
        dinv[i] = rsqrtf((float)v + 1.0f);
        if (i == N - 1) rowptr[N] = excl + v;
    }
}

// ---- scan pass 3 (matrix, transposed read): scannedM[m] -------------------
__global__ void k_scan3t(const unsigned* __restrict__ histG, const unsigned* __restrict__ bsum,
                         unsigned* __restrict__ scannedM, int M, int B) {
    __shared__ unsigned s[TPB];
    int tid = threadIdx.x;
    int i = blockIdx.x * TPB + tid;
    unsigned v = (i < M) ? histG[(i % NB) * B + (i / NB)] : 0u;
    s[tid] = v;
    __syncthreads();
    for (int ofs = 1; ofs < TPB; ofs <<= 1) {
        unsigned t = (tid >= ofs) ? s[tid - ofs] : 0u;
        __syncthreads();
        s[tid] += t;
        __syncthreads();
    }
    if (i < M) scannedM[i] = bsum[blockIdx.x] + s[tid] - v;
}

// ---- level-1 histogram: per-block bucket counts (block-major out) ---------
__global__ void k_bhist(const int* __restrict__ dst, unsigned* __restrict__ histG,
                        int E, int B, int CH) {
    __shared__ unsigned h[MAXB];
    for (int t = threadIdx.x; t < B; t += blockDim.x) h[t] = 0;
    __syncthreads();
    int b = blockIdx.x;
    int beg = b * CH, end = min(E, beg + CH);
    for (int i = beg + threadIdx.x; i < end; i += blockDim.x)
        atomicAdd(&h[dst[i] >> BSH], 1u);
    __syncthreads();
    for (int t = threadIdx.x; t < B; t += blockDim.x) histG[b * B + t] = h[t];
}

// ---- level-1 scatter: packed (src<<8 | dstlo) into bucket-ordered buffer --
__global__ void k_bscatter(const int* __restrict__ src, const int* __restrict__ dst,
                           const unsigned* __restrict__ scannedM, unsigned* __restrict__ lvl1,
                           int E, int B, int CH) {
    __shared__ unsigned cur[MAXB];
    int b = blockIdx.x;
    for (int t = threadIdx.x; t < B; t += blockDim.x) cur[t] = scannedM[t * NB + b];
    __syncthreads();
    int beg = b * CH, end = min(E, beg + CH);
    for (int i = beg + threadIdx.x; i < end; i += blockDim.x) {
        int d = dst[i];
        int bk = d >> BSH;
        unsigned p = atomicAdd(&cur[bk], 1u);
        lvl1[p] = ((unsigned)src[i] << BSH) | (unsigned)(d & ((1 << BSH) - 1));
    }
}

// ---- level-2 build: one block per bucket, rank in LDS, scatter in L2 ------
__global__ void k_bbuild(const unsigned* __restrict__ lvl1, const unsigned* __restrict__ rowptr,
                         int* __restrict__ csr_src, int N) {
    __shared__ unsigned ro[1 << BSH];
    __shared__ unsigned cnt[1 << BSH];
    int b = blockIdx.x;
    int n0 = b << BSH;
    int n1 = min(N, n0 + (1 << BSH));
    int tid = threadIdx.x;
    if (n0 + tid < n1) ro[tid] = rowptr[n0 + tid];
    cnt[tid] = 0;
    __syncthreads();
    unsigned gbase = rowptr[n0], gend = rowptr[n1];
    for (unsigned i = gbase + tid; i < gend; i += (unsigned)blockDim.x) {
        unsigned v = lvl1[i];
        unsigned dlo = v & ((1u << BSH) - 1u);
        unsigned r = atomicAdd(&cnt[dlo], 1u);
        csr_src[ro[dlo] + r] = (int)(v >> BSH);
    }
}

// ---- hs1 = (x @ W1) * dinv[n]   (thread per (node, outch)) ----------------
__global__ void k_lin1(const float* __restrict__ x, const float* __restrict__ W1,
                       const float* __restrict__ dinv, float* __restrict__ hs1, int N) {
    int gid = blockIdx.x * blockDim.x + threadIdx.x;
    if (gid >= N * 32) return;
    int n = gid >> 5, oc = gid & 31;
    const float* xr = x + (size_t)n * 6;
    float s = 0.f;
#pragma unroll
    for (int k = 0; k < 6; ++k) s = fmaf(xr[k], W1[k * 32 + oc], s);
    hs1[gid] = s * dinv[n];
}

// ---- gather aggregation: out[n] = relu(dinv[n]*(self + sum_in hs[src]) + b)
template <int C>
__global__ void k_gagg(const unsigned* __restrict__ rowptr, const int* __restrict__ csr_src,
                       const float* __restrict__ dinv, const float* __restrict__ hs,
                       const float* __restrict__ b, float* __restrict__ outp, int N) {
    constexpr int G = C / 4;
    int gid = blockIdx.x * blockDim.x + threadIdx.x;
    int n = gid / G, g = gid % G;
    if (n >= N) return;
    unsigned beg = rowptr[n], end = rowptr[n + 1];
    const float4* hsv = reinterpret_cast<const float4*>(hs);
    float4 acc = hsv[(size_t)n * G + g];  // self-loop term (hs = h*dinv)
    for (unsigned j = beg; j < end; ++j) {
        int s = csr_src[j];
        float4 v = hsv[(size_t)s * G + g];
        acc.x += v.x; acc.y += v.y; acc.z += v.z; acc.w += v.w;
    }
    float di = dinv[n];
    float4 bb = reinterpret_cast<const float4*>(b)[g];
    float4 r;
    r.x = fmaxf(fmaf(acc.x, di, bb.x), 0.f);
    r.y = fmaxf(fmaf(acc.y, di, bb.y), 0.f);
    r.z = fmaxf(fmaf(acc.z, di, bb.z), 0.f);
    r.w = fmaxf(fmaf(acc.w, di, bb.w), 0.f);
    reinterpret_cast<float4*>(outp)[(size_t)n * G + g] = r;
}

// ---- hs2 = (h1out @ W2) * dinv   (thread per (node, j), j<16) -------------
__global__ void k_lin2(const float* __restrict__ h1out, const float* __restrict__ W2,
                       const float* __restrict__ dinv, float* __restrict__ hs2, int N) {
    int gid = blockIdx.x * blockDim.x + threadIdx.x;
    if (gid >= N * 16) return;
    int n = gid >> 4, j = gid & 15;
    const float* hr = h1out + (size_t)n * 32;
    float acc = 0.f;
#pragma unroll
    for (int c = 0; c < 32; ++c) acc = fmaf(hr[c], W2[c * 16 + j], acc);
    hs2[gid] = acc * dinv[n];
}

// ---- edge MLP: weights via wave-uniform global reads (s_load path) --------
__global__ void __launch_bounds__(TPB) k_edge(
    const int* __restrict__ src, const int* __restrict__ dst,
    const float* __restrict__ h2, const float* __restrict__ eattr,
    const float* __restrict__ W3, const float* __restrict__ b3,
    const float* __restrict__ W4, const float* __restrict__ b4,
    float* __restrict__ out, int E) {
    int e = blockIdx.x * TPB + threadIdx.x;
    if (e >= E) return;
    int s = src[e], d = dst[e];

    float in[40];
    {
        const float4* hs = reinterpret_cast<const float4*>(h2 + (size_t)s * 16);
        const float4* hd = reinterpret_cast<const float4*>(h2 + (size_t)d * 16);
        const float4* ea = reinterpret_cast<const float4*>(eattr + (size_t)e * 8);
#pragma unroll
        for (int q = 0; q < 4; ++q) {
            float4 t = hs[q];
            in[q * 4 + 0] = t.x; in[q * 4 + 1] = t.y; in[q * 4 + 2] = t.z; in[q * 4 + 3] = t.w;
        }
#pragma unroll
        for (int q = 0; q < 4; ++q) {
            float4 t = hd[q];
            in[16 + q * 4 + 0] = t.x; in[16 + q * 4 + 1] = t.y; in[16 + q * 4 + 2] = t.z; in[16 + q * 4 + 3] = t.w;
        }
#pragma unroll
        for (int q = 0; q < 2; ++q) {
            float4 t = ea[q];
            in[32 + q * 4 + 0] = t.x; in[32 + q * 4 + 1] = t.y; in[32 + q * 4 + 2] = t.z; in[32 + q * 4 + 3] = t.w;
        }
    }

    float acc[32];
#pragma unroll
    for (int j = 0; j < 32; ++j) acc[j] = b3[j];  // uniform -> s_load
#pragma unroll
    for (int k = 0; k < 40; ++k) {
        float a = in[k];
#pragma unroll
        for (int j = 0; j < 32; ++j)
            acc[j] = fmaf(a, W3[k * 32 + j], acc[j]);  // uniform weight -> SGPR operand
    }
    float r = b4[0];
#pragma unroll
    for (int j = 0; j < 32; ++j)
        r = fmaf(fmaxf(acc[j], 0.f), W4[j], r);
    out[e] = r;
}

extern "C" void kernel_launch(void* const* d_in, const int* in_sizes, int n_in,
                              void* d_out, int out_size, void* d_ws, size_t ws_size,
                              hipStream_t stream) {
    const float* x     = (const float*)d_in[0];
    const int*   ei    = (const int*)d_in[1];
    const float* eattr = (const float*)d_in[2];
    const float* W1 = (const float*)d_in[3];
    const float* b1 = (const float*)d_in[4];
    const float* W2 = (const float*)d_in[5];
    const float* b2 = (const float*)d_in[6];
    const float* W3 = (const float*)d_in[7];
    const float* b3 = (const float*)d_in[8];
    const float* W4 = (const float*)d_in[9];
    const float* b4 = (const float*)d_in[10];
    float* out = (float*)d_out;

    const int N = in_sizes[0] / 6;     // 100000
    const int E = in_sizes[2] / 8;     // 1600000
    const int* src = ei;
    const int* dst = ei + E;

    const int B  = (N + (1 << BSH) - 1) >> BSH;        // 391 buckets
    const int CH = (E + NB - 1) / NB;                  // 6250 edges/block
    const int M  = B * NB;                             // 100096 matrix entries
    const int nbN = (N + TPB - 1) / TPB;               // 391
    const int nbM = (M + TPB - 1) / TPB;               // 392

    // workspace layout (regions 16B-aligned)
    char* wsb = (char*)d_ws;
    size_t off = 0;
    auto alloc4 = [&](size_t elems) {
        void* p = wsb + off;
        off += ((elems * 4 + 15) & ~(size_t)15);
        return p;
    };
    unsigned* deg      = (unsigned*)alloc4(N);
    unsigned* rowptr   = (unsigned*)alloc4(N + 1);
    float*    dinv     = (float*)alloc4(N);
    unsigned* bsum     = (unsigned*)alloc4(512);
    unsigned* histG    = (unsigned*)alloc4((size_t)NB * B);
    unsigned* scannedM = (unsigned*)alloc4((size_t)NB * B);
    int*      csr_src  = (int*)alloc4(E);
    float*    hs1      = (float*)alloc4((size_t)N * 32);  // also aliases lvl1, hs2, h2
    float*    h1out    = (float*)alloc4((size_t)N * 32);
    unsigned* lvl1 = (unsigned*)hs1;   // E <= N*32; dead before k_lin1 writes hs1
    float*    hs2  = hs1;              // hs1 dead after k_gagg<32>
    float*    h2   = hs1 + (size_t)N * 16;

    hipMemsetAsync(deg, 0, (size_t)N * sizeof(unsigned), stream);

    // per-node degree -> rowptr + dinv
    k_hist <<<(E + TPB - 1) / TPB, TPB, 0, stream>>>(dst, deg, E);
    k_scan1<<<nbN, TPB, 0, stream>>>(deg, bsum, N);
    k_scan2<<<1, 512, 0, stream>>>(bsum, nbN);
    k_scan3<<<nbN, TPB, 0, stream>>>(deg, bsum, rowptr, dinv, N);

    // 2-level bucket sort -> csr_src
    k_bhist   <<<NB, TPB, 0, stream>>>(dst, histG, E, B, CH);
    k_scan1t  <<<nbM, TPB, 0, stream>>>(histG, bsum, M, B);
    k_scan2   <<<1, 512, 0, stream>>>(bsum, nbM);
    k_scan3t  <<<nbM, TPB, 0, stream>>>(histG, bsum, scannedM, M, B);
    k_bscatter<<<NB, TPB, 0, stream>>>(src, dst, scannedM, lvl1, E, B, CH);
    k_bbuild  <<<B, 1 << BSH, 0, stream>>>(lvl1, rowptr, csr_src, N);

    // GCN layer 1 (after k_bbuild: hs1 aliases lvl1)
    k_lin1<<<(N * 32 + TPB - 1) / TPB, TPB, 0, stream>>>(x, W1, dinv, hs1, N);
    k_gagg<32><<<((size_t)N * 8 + TPB - 1) / TPB, TPB, 0, stream>>>(rowptr, csr_src, dinv, hs1, b1, h1out, N);

    // GCN layer 2
    k_lin2<<<(N * 16 + TPB - 1) / TPB, TPB, 0, stream>>>(h1out, W2, dinv, hs2, N);
    k_gagg<16><<<((size_t)N * 4 + TPB - 1) / TPB, TPB, 0, stream>>>(rowptr, csr_src, dinv, hs2, b2, h2, N);

    // edge MLP
    k_edge<<<(E + TPB - 1) / TPB, TPB, 0, stream>>>(src, dst, h2, eattr, W3, b3, W4, b4, out, E);
}

// Round 4
// 208.050 us; speedup vs baseline: 5.7340x; 1.4836x over previous
//
#include <hip/hip_runtime.h>

// EdgeWeightPredictor: 2-layer GCN (sym-norm, self-loops) + edge MLP.
// N=100000 nodes (IN_CH=6), E=1600000 edges (EDGE_FEAT=8).
// Round 4: bf16 feature tables for all gathered data (halves gather traffic;
// h2/hs2 now fit per-XCD L2); degree/rowptr/dinv folded into k_bbuild
// (k_hist + 3 scans + memset deleted).

constexpr int TPB = 256;
constexpr int NB = 256;         // level-1 blocks
constexpr int BSH = 8;          // 256 nodes per bucket
constexpr int MAXB = 1024;      // max buckets supported (N <= 262144)

// ---- bf16 pack/unpack (RTNE) ----------------------------------------------
__device__ __forceinline__ float bf_lo(unsigned w) {
    return __builtin_bit_cast(float, (unsigned)(w << 16));
}
__device__ __forceinline__ float bf_hi(unsigned w) {
    return __builtin_bit_cast(float, w & 0xFFFF0000u);
}
__device__ __forceinline__ unsigned bf1(float f) {
    unsigned u = __builtin_bit_cast(unsigned, f);
    return (u + 0x7FFFu + ((u >> 16) & 1u)) >> 16;
}
__device__ __forceinline__ unsigned pk(float lo, float hi) {
    return bf1(lo) | (bf1(hi) << 16);
}
__device__ __forceinline__ void unp8(uint4 v, float* o) {
    o[0] = bf_lo(v.x); o[1] = bf_hi(v.x); o[2] = bf_lo(v.y); o[3] = bf_hi(v.y);
    o[4] = bf_lo(v.z); o[5] = bf_hi(v.z); o[6] = bf_lo(v.w); o[7] = bf_hi(v.w);
}

// ---- level-1 histogram: per-block bucket counts (block-major out) ---------
__global__ void k_bhist(const int* __restrict__ dst, unsigned* __restrict__ histG,
                        int E, int B, int CH) {
    __shared__ unsigned h[MAXB];
    for (int t = threadIdx.x; t < B; t += blockDim.x) h[t] = 0;
    __syncthreads();
    int b = blockIdx.x;
    int beg = b * CH, end = min(E, beg + CH);
    for (int i = beg + threadIdx.x; i < end; i += blockDim.x)
        atomicAdd(&h[dst[i] >> BSH], 1u);
    __syncthreads();
    for (int t = threadIdx.x; t < B; t += blockDim.x) histG[b * B + t] = h[t];
}

// ---- scan pass 1 (transposed read: m = bucket*NB + block) -----------------
__global__ void k_scan1t(const unsigned* __restrict__ histG, unsigned* __restrict__ bsum,
                         int M, int B) {
    __shared__ unsigned s[TPB];
    int tid = threadIdx.x;
    int i = blockIdx.x * TPB + tid;
    unsigned v = (i < M) ? histG[(i % NB) * B + (i / NB)] : 0u;
    s[tid] = v;
    __syncthreads();
    for (int ofs = TPB / 2; ofs > 0; ofs >>= 1) {
        if (tid < ofs) s[tid] += s[tid + ofs];
        __syncthreads();
    }
    if (tid == 0) bsum[blockIdx.x] = s[0];
}

// ---- scan pass 2: exclusive scan of block sums (1 block, 512 thr) ---------
__global__ void k_scan2(unsigned* __restrict__ bsum, int nb) {
    __shared__ unsigned s[512];
    int tid = threadIdx.x;
    unsigned v = (tid < nb) ? bsum[tid] : 0u;
    s[tid] = v;
    __syncthreads();
    for (int ofs = 1; ofs < 512; ofs <<= 1) {
        unsigned t = (tid >= ofs) ? s[tid - ofs] : 0u;
        __syncthreads();
        s[tid] += t;
        __syncthreads();
    }
    if (tid < nb) bsum[tid] = s[tid] - v;  // exclusive
}

// ---- scan pass 3 (transposed read): scannedM[m] ---------------------------
__global__ void k_scan3t(const unsigned* __restrict__ histG, const unsigned* __restrict__ bsum,
                         unsigned* __restrict__ scannedM, int M, int B) {
    __shared__ unsigned s[TPB];
    int tid = threadIdx.x;
    int i = blockIdx.x * TPB + tid;
    unsigned v = (i < M) ? histG[(i % NB) * B + (i / NB)] : 0u;
    s[tid] = v;
    __syncthreads();
    for (int ofs = 1; ofs < TPB; ofs <<= 1) {
        unsigned t = (tid >= ofs) ? s[tid - ofs] : 0u;
        __syncthreads();
        s[tid] += t;
        __syncthreads();
    }
    if (i < M) scannedM[i] = bsum[blockIdx.x] + s[tid] - v;
}

// ---- level-1 scatter: packed (src<<8 | dstlo) into bucket-ordered buffer --
__global__ void k_bscatter(const int* __restrict__ src, const int* __restrict__ dst,
                           const unsigned* __restrict__ scannedM, unsigned* __restrict__ lvl1,
                           int E, int B, int CH) {
    __shared__ unsigned cur[MAXB];
    int b = blockIdx.x;
    for (int t = threadIdx.x; t < B; t += blockDim.x) cur[t] = scannedM[t * NB + b];
    __syncthreads();
    int beg = b * CH, end = min(E, beg + CH);
    for (int i = beg + threadIdx.x; i < end; i += blockDim.x) {
        int d = dst[i];
        int bk = d >> BSH;
        unsigned p = atomicAdd(&cur[bk], 1u);
        lvl1[p] = ((unsigned)src[i] << BSH) | (unsigned)(d & ((1 << BSH) - 1));
    }
}

// ---- level-2 build: count + local scan -> rowptr/dinv; then place csr_src -
__global__ void k_bbuild(const unsigned* __restrict__ lvl1, const unsigned* __restrict__ scannedM,
                         unsigned* __restrict__ rowptr, float* __restrict__ dinv,
                         int* __restrict__ csr_src, int N, int E, int B) {
    __shared__ unsigned cnt[1 << BSH];
    __shared__ unsigned ro[1 << BSH];
    int b = blockIdx.x;
    int tid = threadIdx.x;
    unsigned gbase = scannedM[(size_t)b * NB];
    unsigned gend = (b + 1 < B) ? scannedM[(size_t)(b + 1) * NB] : (unsigned)E;
    cnt[tid] = 0;
    __syncthreads();
    for (unsigned i = gbase + tid; i < gend; i += (unsigned)blockDim.x)
        atomicAdd(&cnt[lvl1[i] & ((1u << BSH) - 1u)], 1u);
    __syncthreads();
    unsigned v = cnt[tid];
    ro[tid] = v;
    __syncthreads();
    for (int ofs = 1; ofs < (1 << BSH); ofs <<= 1) {
        unsigned t = (tid >= ofs) ? ro[tid - ofs] : 0u;
        __syncthreads();
        ro[tid] += t;
        __syncthreads();
    }
    unsigned excl = ro[tid] - v;  // exclusive within bucket
    int n = (b << BSH) + tid;
    if (n < N) {
        rowptr[n] = gbase + excl;
        dinv[n] = rsqrtf((float)v + 1.0f);
        if (n == N - 1) rowptr[N] = gend;
    }
    __syncthreads();
    cnt[tid] = gbase + excl;  // absolute write cursor
    __syncthreads();
    for (unsigned i = gbase + tid; i < gend; i += (unsigned)blockDim.x) {
        unsigned w = lvl1[i];
        unsigned p = atomicAdd(&cnt[w & ((1u << BSH) - 1u)], 1u);
        csr_src[p] = (int)(w >> BSH);
    }
}

// ---- hs1 = bf16((x @ W1) * dinv[n])   (thread per (node, ch-pair<16)) -----
__global__ void k_lin1(const float* __restrict__ x, const float* __restrict__ W1,
                       const float* __restrict__ dinv, unsigned* __restrict__ hs1, int N) {
    int gid = blockIdx.x * blockDim.x + threadIdx.x;
    if (gid >= N * 16) return;
    int n = gid >> 4, p = gid & 15;
    const float* xr = x + (size_t)n * 6;
    float s0 = 0.f, s1 = 0.f;
#pragma unroll
    for (int k = 0; k < 6; ++k) {
        float a = xr[k];
        s0 = fmaf(a, W1[k * 32 + 2 * p], s0);
        s1 = fmaf(a, W1[k * 32 + 2 * p + 1], s1);
    }
    float di = dinv[n];
    hs1[gid] = pk(s0 * di, s1 * di);
}

// ---- gather aggregation (bf16 in): out[n] = relu(dinv*(self+sum)+b) -------
// C channels; C/8 lanes per node; each lane: uint4 = 8 bf16 channels.
template <int C, bool BF16OUT>
__global__ void k_gagg(const unsigned* __restrict__ rowptr, const int* __restrict__ csr_src,
                       const float* __restrict__ dinv, const uint4* __restrict__ hs,
                       const float* __restrict__ b, uint4* __restrict__ out_bf,
                       float* __restrict__ out_f32, int N) {
    constexpr int G = C / 8;
    int gid = blockIdx.x * blockDim.x + threadIdx.x;
    int n = gid / G, g = gid % G;
    if (n >= N) return;
    unsigned beg = rowptr[n], end = rowptr[n + 1];
    float acc[8];
    unp8(hs[(size_t)n * G + g], acc);  // self-loop term (hs = h*dinv)
    for (unsigned j = beg; j < end; ++j) {
        int s = csr_src[j];
        float t[8];
        unp8(hs[(size_t)s * G + g], t);
#pragma unroll
        for (int i = 0; i < 8; ++i) acc[i] += t[i];
    }
    float di = dinv[n];
    float r[8];
#pragma unroll
    for (int i = 0; i < 8; ++i) r[i] = fmaxf(fmaf(acc[i], di, b[g * 8 + i]), 0.f);
    if (BF16OUT) {
        uint4 o;
        o.x = pk(r[0], r[1]); o.y = pk(r[2], r[3]);
        o.z = pk(r[4], r[5]); o.w = pk(r[6], r[7]);
        out_bf[(size_t)n * G + g] = o;
    } else {
        float4* op = reinterpret_cast<float4*>(out_f32 + (size_t)n * C + g * 8);
        op[0] = float4{r[0], r[1], r[2], r[3]};
        op[1] = float4{r[4], r[5], r[6], r[7]};
    }
}

// ---- hs2 = bf16((h1out @ W2) * dinv)   (thread per (node, ch-pair<8)) -----
__global__ void k_lin2(const float* __restrict__ h1out, const float* __restrict__ W2,
                       const float* __restrict__ dinv, unsigned* __restrict__ hs2, int N) {
    int gid = blockIdx.x * blockDim.x + threadIdx.x;
    if (gid >= N * 8) return;
    int n = gid >> 3, p = gid & 7;
    const float* hr = h1out + (size_t)n * 32;
    float s0 = 0.f, s1 = 0.f;
#pragma unroll
    for (int c = 0; c < 32; ++c) {
        float a = hr[c];
        s0 = fmaf(a, W2[c * 16 + 2 * p], s0);
        s1 = fmaf(a, W2[c * 16 + 2 * p + 1], s1);
    }
    float di = dinv[n];
    hs2[gid] = pk(s0 * di, s1 * di);
}

// ---- edge MLP: bf16 h2 gathers; weights via wave-uniform reads ------------
__global__ void __launch_bounds__(TPB) k_edge(
    const int* __restrict__ src, const int* __restrict__ dst,
    const uint4* __restrict__ h2, const float* __restrict__ eattr,
    const float* __restrict__ W3, const float* __restrict__ b3,
    const float* __restrict__ W4, const float* __restrict__ b4,
    float* __restrict__ out, int E) {
    int e = blockIdx.x * TPB + threadIdx.x;
    if (e >= E) return;
    int s = src[e], d = dst[e];

    float in[40];
    uint4 sa = h2[(size_t)s * 2], sb = h2[(size_t)s * 2 + 1];
    uint4 da = h2[(size_t)d * 2], db = h2[(size_t)d * 2 + 1];
    unp8(sa, in); unp8(sb, in + 8); unp8(da, in + 16); unp8(db, in + 24);
    const float4* ea = reinterpret_cast<const float4*>(eattr + (size_t)e * 8);
    float4 e0 = ea[0], e1 = ea[1];
    in[32] = e0.x; in[33] = e0.y; in[34] = e0.z; in[35] = e0.w;
    in[36] = e1.x; in[37] = e1.y; in[38] = e1.z; in[39] = e1.w;

    float acc[32];
#pragma unroll
    for (int j = 0; j < 32; ++j) acc[j] = b3[j];  // uniform -> s_load
#pragma unroll
    for (int k = 0; k < 40; ++k) {
        float a = in[k];
#pragma unroll
        for (int j = 0; j < 32; ++j)
            acc[j] = fmaf(a, W3[k * 32 + j], acc[j]);  // uniform weight -> SGPR operand
    }
    float r = b4[0];
#pragma unroll
    for (int j = 0; j < 32; ++j)
        r = fmaf(fmaxf(acc[j], 0.f), W4[j], r);
    out[e] = r;
}

extern "C" void kernel_launch(void* const* d_in, const int* in_sizes, int n_in,
                              void* d_out, int out_size, void* d_ws, size_t ws_size,
                              hipStream_t stream) {
    const float* x     = (const float*)d_in[0];
    const int*   ei    = (const int*)d_in[1];
    const float* eattr = (const float*)d_in[2];
    const float* W1 = (const float*)d_in[3];
    const float* b1 = (const float*)d_in[4];
    const float* W2 = (const float*)d_in[5];
    const float* b2 = (const float*)d_in[6];
    const float* W3 = (const float*)d_in[7];
    const float* b3 = (const float*)d_in[8];
    const float* W4 = (const float*)d_in[9];
    const float* b4 = (const float*)d_in[10];
    float* out = (float*)d_out;

    const int N = in_sizes[0] / 6;     // 100000
    const int E = in_sizes[2] / 8;     // 1600000
    const int* src = ei;
    const int* dst = ei + E;

    const int B  = (N + (1 << BSH) - 1) >> BSH;        // 391 buckets
    const int CH = (E + NB - 1) / NB;                  // 6250 edges/block
    const int M  = B * NB;                             // 100096
    const int nbM = (M + TPB - 1) / TPB;               // 392 (<=512)

    // workspace layout (regions 16B-aligned)
    char* wsb = (char*)d_ws;
    size_t off = 0;
    auto alloc4 = [&](size_t elems) {
        void* p = wsb + off;
        off += ((elems * 4 + 15) & ~(size_t)15);
        return p;
    };
    unsigned* rowptr   = (unsigned*)alloc4(N + 1);
    float*    dinv     = (float*)alloc4(N);
    unsigned* bsum     = (unsigned*)alloc4(512);
    unsigned* histG    = (unsigned*)alloc4((size_t)NB * B);
    unsigned* scannedM = (unsigned*)alloc4((size_t)NB * B);
    int*      csr_src  = (int*)alloc4(E);
    unsigned* big      = (unsigned*)alloc4((size_t)N * 16 > (size_t)E ? (size_t)N * 16 : (size_t)E);
    float*    h1out    = (float*)alloc4((size_t)N * 32);

    unsigned* lvl1 = big;                    // E u32 (dead before k_lin1)
    unsigned* hs1  = big;                    // N*16 u32 (bf16 pairs, 32ch)
    unsigned* hs2  = big;                    // N*8 u32 (bf16 pairs, 16ch; hs1 dead)
    uint4*    h2   = (uint4*)(big + (size_t)N * 8);  // N*2 uint4 (bf16, 16ch)

    // bucket sort -> rowptr/dinv/csr_src (no global atomics on floats, no memset)
    k_bhist   <<<NB, TPB, 0, stream>>>(dst, histG, E, B, CH);
    k_scan1t  <<<nbM, TPB, 0, stream>>>(histG, bsum, M, B);
    k_scan2   <<<1, 512, 0, stream>>>(bsum, nbM);
    k_scan3t  <<<nbM, TPB, 0, stream>>>(histG, bsum, scannedM, M, B);
    k_bscatter<<<NB, TPB, 0, stream>>>(src, dst, scannedM, lvl1, E, B, CH);
    k_bbuild  <<<B, 1 << BSH, 0, stream>>>(lvl1, scannedM, rowptr, dinv, csr_src, N, E, B);

    // GCN layer 1
    k_lin1<<<(N * 16 + TPB - 1) / TPB, TPB, 0, stream>>>(x, W1, dinv, hs1, N);
    k_gagg<32, false><<<((size_t)N * 4 + TPB - 1) / TPB, TPB, 0, stream>>>(
        rowptr, csr_src, dinv, (const uint4*)hs1, b1, nullptr, h1out, N);

    // GCN layer 2
    k_lin2<<<(N * 8 + TPB - 1) / TPB, TPB, 0, stream>>>(h1out, W2, dinv, hs2, N);
    k_gagg<16, true><<<((size_t)N * 2 + TPB - 1) / TPB, TPB, 0, stream>>>(
        rowptr, csr_src, dinv, (const uint4*)hs2, b2, h2, nullptr, N);

    // edge MLP
    k_edge<<<(E + TPB - 1) / TPB, TPB, 0, stream>>>(src, dst, (const uint4*)h2, eattr,
                                                    W3, b3, W4, b4, out, E);
}

// Round 5
// 180.580 us; speedup vs baseline: 6.6063x; 1.1521x over previous
//
#include <hip/hip_runtime.h>

// EdgeWeightPredictor: 2-layer GCN (sym-norm, self-loops) + edge MLP.
// N=100000 nodes (IN_CH=6), E=1600000 edges (EDGE_FEAT=8).
// Round 5: edge MLP on MFMA (mfma_f32_16x16x32_bf16). One wave = 16 edges;
// A fragments come straight from the bf16 h2 table (one uint4 per lane) +
// eattr on kb==0 lanes; W3 fragments built once per thread, amortized over
// 16 tiles. Epilogue: relu + W4 via shfl_xor column reduce.

constexpr int TPB = 256;
constexpr int NB = 256;         // level-1 blocks
constexpr int BSH = 8;          // 256 nodes per bucket
constexpr int MAXB = 1024;      // max buckets supported (N <= 262144)
constexpr int EDGE_ITERS = 16;  // 16-edge tiles per wave

using short8 = __attribute__((ext_vector_type(8))) short;
using f32x4  = __attribute__((ext_vector_type(4))) float;

// ---- bf16 pack/unpack (RTNE) ----------------------------------------------
__device__ __forceinline__ float bf_lo(unsigned w) {
    return __builtin_bit_cast(float, (unsigned)(w << 16));
}
__device__ __forceinline__ float bf_hi(unsigned w) {
    return __builtin_bit_cast(float, w & 0xFFFF0000u);
}
__device__ __forceinline__ unsigned bf1(float f) {
    unsigned u = __builtin_bit_cast(unsigned, f);
    return (u + 0x7FFFu + ((u >> 16) & 1u)) >> 16;
}
__device__ __forceinline__ unsigned pk(float lo, float hi) {
    return bf1(lo) | (bf1(hi) << 16);
}
__device__ __forceinline__ void unp8(uint4 v, float* o) {
    o[0] = bf_lo(v.x); o[1] = bf_hi(v.x); o[2] = bf_lo(v.y); o[3] = bf_hi(v.y);
    o[4] = bf_lo(v.z); o[5] = bf_hi(v.z); o[6] = bf_lo(v.w); o[7] = bf_hi(v.w);
}

// ---- level-1 histogram: per-block bucket counts (block-major out) ---------
__global__ void k_bhist(const int* __restrict__ dst, unsigned* __restrict__ histG,
                        int E, int B, int CH) {
    __shared__ unsigned h[MAXB];
    for (int t = threadIdx.x; t < B; t += blockDim.x) h[t] = 0;
    __syncthreads();
    int b = blockIdx.x;
    int beg = b * CH, end = min(E, beg + CH);
    for (int i = beg + threadIdx.x; i < end; i += blockDim.x)
        atomicAdd(&h[dst[i] >> BSH], 1u);
    __syncthreads();
    for (int t = threadIdx.x; t < B; t += blockDim.x) histG[b * B + t] = h[t];
}

// ---- scan pass 1 (transposed read: m = bucket*NB + block) -----------------
__global__ void k_scan1t(const unsigned* __restrict__ histG, unsigned* __restrict__ bsum,
                         int M, int B) {
    __shared__ unsigned s[TPB];
    int tid = threadIdx.x;
    int i = blockIdx.x * TPB + tid;
    unsigned v = (i < M) ? histG[(i % NB) * B + (i / NB)] : 0u;
    s[tid] = v;
    __syncthreads();
    for (int ofs = TPB / 2; ofs > 0; ofs >>= 1) {
        if (tid < ofs) s[tid] += s[tid + ofs];
        __syncthreads();
    }
    if (tid == 0) bsum[blockIdx.x] = s[0];
}

// ---- scan pass 2: exclusive scan of block sums (1 block, 512 thr) ---------
__global__ void k_scan2(unsigned* __restrict__ bsum, int nb) {
    __shared__ unsigned s[512];
    int tid = threadIdx.x;
    unsigned v = (tid < nb) ? bsum[tid] : 0u;
    s[tid] = v;
    __syncthreads();
    for (int ofs = 1; ofs < 512; ofs <<= 1) {
        unsigned t = (tid >= ofs) ? s[tid - ofs] : 0u;
        __syncthreads();
        s[tid] += t;
        __syncthreads();
    }
    if (tid < nb) bsum[tid] = s[tid] - v;  // exclusive
}

// ---- scan pass 3 (transposed read): scannedM[m] ---------------------------
__global__ void k_scan3t(const unsigned* __restrict__ histG, const unsigned* __restrict__ bsum,
                         unsigned* __restrict__ scannedM, int M, int B) {
    __shared__ unsigned s[TPB];
    int tid = threadIdx.x;
    int i = blockIdx.x * TPB + tid;
    unsigned v = (i < M) ? histG[(i % NB) * B + (i / NB)] : 0u;
    s[tid] = v;
    __syncthreads();
    for (int ofs = 1; ofs < TPB; ofs <<= 1) {
        unsigned t = (tid >= ofs) ? s[tid - ofs] : 0u;
        __syncthreads();
        s[tid] += t;
        __syncthreads();
    }
    if (i < M) scannedM[i] = bsum[blockIdx.x] + s[tid] - v;
}

// ---- level-1 scatter: packed (src<<8 | dstlo) into bucket-ordered buffer --
__global__ void k_bscatter(const int* __restrict__ src, const int* __restrict__ dst,
                           const unsigned* __restrict__ scannedM, unsigned* __restrict__ lvl1,
                           int E, int B, int CH) {
    __shared__ unsigned cur[MAXB];
    int b = blockIdx.x;
    for (int t = threadIdx.x; t < B; t += blockDim.x) cur[t] = scannedM[t * NB + b];
    __syncthreads();
    int beg = b * CH, end = min(E, beg + CH);
    for (int i = beg + threadIdx.x; i < end; i += blockDim.x) {
        int d = dst[i];
        int bk = d >> BSH;
        unsigned p = atomicAdd(&cur[bk], 1u);
        lvl1[p] = ((unsigned)src[i] << BSH) | (unsigned)(d & ((1 << BSH) - 1));
    }
}

// ---- level-2 build: count + local scan -> rowptr/dinv; then place csr_src -
__global__ void k_bbuild(const unsigned* __restrict__ lvl1, const unsigned* __restrict__ scannedM,
                         unsigned* __restrict__ rowptr, float* __restrict__ dinv,
                         int* __restrict__ csr_src, int N, int E, int B) {
    __shared__ unsigned cnt[1 << BSH];
    __shared__ unsigned ro[1 << BSH];
    int b = blockIdx.x;
    int tid = threadIdx.x;
    unsigned gbase = scannedM[(size_t)b * NB];
    unsigned gend = (b + 1 < B) ? scannedM[(size_t)(b + 1) * NB] : (unsigned)E;
    cnt[tid] = 0;
    __syncthreads();
    for (unsigned i = gbase + tid; i < gend; i += (unsigned)blockDim.x)
        atomicAdd(&cnt[lvl1[i] & ((1u << BSH) - 1u)], 1u);
    __syncthreads();
    unsigned v = cnt[tid];
    ro[tid] = v;
    __syncthreads();
    for (int ofs = 1; ofs < (1 << BSH); ofs <<= 1) {
        unsigned t = (tid >= ofs) ? ro[tid - ofs] : 0u;
        __syncthreads();
        ro[tid] += t;
        __syncthreads();
    }
    unsigned excl = ro[tid] - v;  // exclusive within bucket
    int n = (b << BSH) + tid;
    if (n < N) {
        rowptr[n] = gbase + excl;
        dinv[n] = rsqrtf((float)v + 1.0f);
        if (n == N - 1) rowptr[N] = gend;
    }
    __syncthreads();
    cnt[tid] = gbase + excl;  // absolute write cursor
    __syncthreads();
    for (unsigned i = gbase + tid; i < gend; i += (unsigned)blockDim.x) {
        unsigned w = lvl1[i];
        unsigned p = atomicAdd(&cnt[w & ((1u << BSH) - 1u)], 1u);
        csr_src[p] = (int)(w >> BSH);
    }
}

// ---- hs1 = bf16((x @ W1) * dinv[n])   (thread per (node, ch-pair<16)) -----
__global__ void k_lin1(const float* __restrict__ x, const float* __restrict__ W1,
                       const float* __restrict__ dinv, unsigned* __restrict__ hs1, int N) {
    int gid = blockIdx.x * blockDim.x + threadIdx.x;
    if (gid >= N * 16) return;
    int n = gid >> 4, p = gid & 15;
    const float* xr = x + (size_t)n * 6;
    float s0 = 0.f, s1 = 0.f;
#pragma unroll
    for (int k = 0; k < 6; ++k) {
        float a = xr[k];
        s0 = fmaf(a, W1[k * 32 + 2 * p], s0);
        s1 = fmaf(a, W1[k * 32 + 2 * p + 1], s1);
    }
    float di = dinv[n];
    hs1[gid] = pk(s0 * di, s1 * di);
}

// ---- gather aggregation (bf16 in): out[n] = relu(dinv*(self+sum)+b) -------
template <int C, bool BF16OUT>
__global__ void k_gagg(const unsigned* __restrict__ rowptr, const int* __restrict__ csr_src,
                       const float* __restrict__ dinv, const uint4* __restrict__ hs,
                       const float* __restrict__ b, uint4* __restrict__ out_bf,
                       float* __restrict__ out_f32, int N) {
    constexpr int G = C / 8;
    int gid = blockIdx.x * blockDim.x + threadIdx.x;
    int n = gid / G, g = gid % G;
    if (n >= N) return;
    unsigned beg = rowptr[n], end = rowptr[n + 1];
    float acc[8];
    unp8(hs[(size_t)n * G + g], acc);  // self-loop term (hs = h*dinv)
    for (unsigned j = beg; j < end; ++j) {
        int s = csr_src[j];
        float t[8];
        unp8(hs[(size_t)s * G + g], t);
#pragma unroll
        for (int i = 0; i < 8; ++i) acc[i] += t[i];
    }
    float di = dinv[n];
    float r[8];
#pragma unroll
    for (int i = 0; i < 8; ++i) r[i] = fmaxf(fmaf(acc[i], di, b[g * 8 + i]), 0.f);
    if (BF16OUT) {
        uint4 o;
        o.x = pk(r[0], r[1]); o.y = pk(r[2], r[3]);
        o.z = pk(r[4], r[5]); o.w = pk(r[6], r[7]);
        out_bf[(size_t)n * G + g] = o;
    } else {
        float4* op = reinterpret_cast<float4*>(out_f32 + (size_t)n * C + g * 8);
        op[0] = float4{r[0], r[1], r[2], r[3]};
        op[1] = float4{r[4], r[5], r[6], r[7]};
    }
}

// ---- hs2 = bf16((h1out @ W2) * dinv)   (thread per (node, ch-pair<8)) -----
__global__ void k_lin2(const float* __restrict__ h1out, const float* __restrict__ W2,
                       const float* __restrict__ dinv, unsigned* __restrict__ hs2, int N) {
    int gid = blockIdx.x * blockDim.x + threadIdx.x;
    if (gid >= N * 8) return;
    int n = gid >> 3, p = gid & 7;
    const float* hr = h1out + (size_t)n * 32;
    float s0 = 0.f, s1 = 0.f;
#pragma unroll
    for (int c = 0; c < 32; ++c) {
        float a = hr[c];
        s0 = fmaf(a, W2[c * 16 + 2 * p], s0);
        s1 = fmaf(a, W2[c * 16 + 2 * p + 1], s1);
    }
    float di = dinv[n];
    hs2[gid] = pk(s0 * di, s1 * di);
}

// ---- edge MLP via MFMA -----------------------------------------------------
// One wave per 16-edge tile, EDGE_ITERS tiles per wave.
// A[16 edges][K=64 pad]: lane(l15=row, kb=l>>4): k-chunk kb*8..kb*8+7.
//   k-step0 (k 0..31): kb 0,1 -> h2[src] uint4 halves; kb 2,3 -> h2[dst].
//   k-step1 (k 32..63): kb==0 -> eattr (8 ch, bf16-packed); else zero.
// B[k][j]: lane(col=l15, k-chunk kb); two N-tiles (j 0-15, 16-31).
// C: col(j)=l15, row(edge)=kb*4+reg (guide-verified layout).
__global__ void __launch_bounds__(TPB) k_edge_mfma(
    const int* __restrict__ src, const int* __restrict__ dst,
    const uint4* __restrict__ h2, const float* __restrict__ eattr,
    const float* __restrict__ W3, const float* __restrict__ b3,
    const float* __restrict__ W4, const float* __restrict__ b4,
    float* __restrict__ out, int E) {
    const int lane = threadIdx.x & 63;
    const int wave = threadIdx.x >> 6;
    const int l15 = lane & 15;
    const int kb = lane >> 4;

    // W3 fragments (bf16), built once per thread
    short8 bf0[2], bf1v[2];
    {
        unsigned w0[2][4], w1[2][4];
#pragma unroll
        for (int t = 0; t < 2; ++t) {
#pragma unroll
            for (int p = 0; p < 4; ++p) {
                int k0 = kb * 8 + 2 * p;
                w0[t][p] = pk(W3[k0 * 32 + t * 16 + l15], W3[(k0 + 1) * 32 + t * 16 + l15]);
                int k1 = 32 + kb * 8 + 2 * p;
                float f0 = (k1 < 40) ? W3[k1 * 32 + t * 16 + l15] : 0.f;
                float f1 = (k1 + 1 < 40) ? W3[(k1 + 1) * 32 + t * 16 + l15] : 0.f;
                w1[t][p] = pk(f0, f1);
            }
        }
        bf0[0] = __builtin_bit_cast(short8, uint4{w0[0][0], w0[0][1], w0[0][2], w0[0][3]});
        bf0[1] = __builtin_bit_cast(short8, uint4{w0[1][0], w0[1][1], w0[1][2], w0[1][3]});
        bf1v[0] = __builtin_bit_cast(short8, uint4{w1[0][0], w1[0][1], w1[0][2], w1[0][3]});
        bf1v[1] = __builtin_bit_cast(short8, uint4{w1[1][0], w1[1][1], w1[1][2], w1[1][3]});
    }
    const float b3a = b3[l15], b3b = b3[16 + l15];
    const float w4a = W4[l15], w4b = W4[16 + l15];
    const float b4v = b4[0];
    const int* idx_tab = (kb >= 2) ? dst : src;

    long base0 = ((long)blockIdx.x * 4 + wave) * (16L * EDGE_ITERS);
    for (int it = 0; it < EDGE_ITERS; ++it) {
        long ebase = base0 + (long)it * 16;
        long et = ebase + l15;
        int e_ld = (int)(et < E ? et : (long)(E - 1));
        int idx = idx_tab[e_ld];
        uint4 hv = h2[(size_t)idx * 2 + (kb & 1)];
        short8 a0 = __builtin_bit_cast(short8, hv);
        short8 a1 = __builtin_bit_cast(short8, uint4{0u, 0u, 0u, 0u});
        if (kb == 0) {
            const float4* ea = reinterpret_cast<const float4*>(eattr + (size_t)e_ld * 8);
            float4 e0 = ea[0], e1 = ea[1];
            a1 = __builtin_bit_cast(short8, uint4{pk(e0.x, e0.y), pk(e0.z, e0.w),
                                                  pk(e1.x, e1.y), pk(e1.z, e1.w)});
        }
        f32x4 c0 = {0.f, 0.f, 0.f, 0.f}, c1 = {0.f, 0.f, 0.f, 0.f};
        c0 = __builtin_amdgcn_mfma_f32_16x16x32_bf16(a0, bf0[0], c0, 0, 0, 0);
        c0 = __builtin_amdgcn_mfma_f32_16x16x32_bf16(a1, bf1v[0], c0, 0, 0, 0);
        c1 = __builtin_amdgcn_mfma_f32_16x16x32_bf16(a0, bf0[1], c1, 0, 0, 0);
        c1 = __builtin_amdgcn_mfma_f32_16x16x32_bf16(a1, bf1v[1], c1, 0, 0, 0);
#pragma unroll
        for (int reg = 0; reg < 4; ++reg) {
            float z = fmaf(fmaxf(c0[reg] + b3a, 0.f), w4a,
                           fmaxf(c1[reg] + b3b, 0.f) * w4b);
            z += __shfl_xor(z, 1);
            z += __shfl_xor(z, 2);
            z += __shfl_xor(z, 4);
            z += __shfl_xor(z, 8);
            long erow = ebase + kb * 4 + reg;
            if (l15 == reg && erow < E) out[erow] = z + b4v;
        }
    }
}

extern "C" void kernel_launch(void* const* d_in, const int* in_sizes, int n_in,
                              void* d_out, int out_size, void* d_ws, size_t ws_size,
                              hipStream_t stream) {
    const float* x     = (const float*)d_in[0];
    const int*   ei    = (const int*)d_in[1];
    const float* eattr = (const float*)d_in[2];
    const float* W1 = (const float*)d_in[3];
    const float* b1 = (const float*)d_in[4];
    const float* W2 = (const float*)d_in[5];
    const float* b2 = (const float*)d_in[6];
    const float* W3 = (const float*)d_in[7];
    const float* b3 = (const float*)d_in[8];
    const float* W4 = (const float*)d_in[9];
    const float* b4 = (const float*)d_in[10];
    float* out = (float*)d_out;

    const int N = in_sizes[0] / 6;     // 100000
    const int E = in_sizes[2] / 8;     // 1600000
    const int* src = ei;
    const int* dst = ei + E;

    const int B  = (N + (1 << BSH) - 1) >> BSH;        // 391 buckets
    const int CH = (E + NB - 1) / NB;                  // 6250 edges/block
    const int M  = B * NB;                             // 100096
    const int nbM = (M + TPB - 1) / TPB;               // 392 (<=512)

    // workspace layout (regions 16B-aligned)
    char* wsb = (char*)d_ws;
    size_t off = 0;
    auto alloc4 = [&](size_t elems) {
        void* p = wsb + off;
        off += ((elems * 4 + 15) & ~(size_t)15);
        return p;
    };
    unsigned* rowptr   = (unsigned*)alloc4(N + 1);
    float*    dinv     = (float*)alloc4(N);
    unsigned* bsum     = (unsigned*)alloc4(512);
    unsigned* histG    = (unsigned*)alloc4((size_t)NB * B);
    unsigned* scannedM = (unsigned*)alloc4((size_t)NB * B);
    int*      csr_src  = (int*)alloc4(E);
    unsigned* big      = (unsigned*)alloc4((size_t)N * 16 > (size_t)E ? (size_t)N * 16 : (size_t)E);
    float*    h1out    = (float*)alloc4((size_t)N * 32);

    unsigned* lvl1 = big;                    // E u32 (dead before k_lin1)
    unsigned* hs1  = big;                    // N*16 u32 (bf16 pairs, 32ch)
    unsigned* hs2  = big;                    // N*8 u32 (bf16 pairs, 16ch; hs1 dead)
    uint4*    h2   = (uint4*)(big + (size_t)N * 8);  // N*2 uint4 (bf16, 16ch)

    // bucket sort -> rowptr/dinv/csr_src
    k_bhist   <<<NB, TPB, 0, stream>>>(dst, histG, E, B, CH);
    k_scan1t  <<<nbM, TPB, 0, stream>>>(histG, bsum, M, B);
    k_scan2   <<<1, 512, 0, stream>>>(bsum, nbM);
    k_scan3t  <<<nbM, TPB, 0, stream>>>(histG, bsum, scannedM, M, B);
    k_bscatter<<<NB, TPB, 0, stream>>>(src, dst, scannedM, lvl1, E, B, CH);
    k_bbuild  <<<B, 1 << BSH, 0, stream>>>(lvl1, scannedM, rowptr, dinv, csr_src, N, E, B);

    // GCN layer 1
    k_lin1<<<(N * 16 + TPB - 1) / TPB, TPB, 0, stream>>>(x, W1, dinv, hs1, N);
    k_gagg<32, false><<<((size_t)N * 4 + TPB - 1) / TPB, TPB, 0, stream>>>(
        rowptr, csr_src, dinv, (const uint4*)hs1, b1, nullptr, h1out, N);

    // GCN layer 2
    k_lin2<<<(N * 8 + TPB - 1) / TPB, TPB, 0, stream>>>(h1out, W2, dinv, hs2, N);
    k_gagg<16, true><<<((size_t)N * 2 + TPB - 1) / TPB, TPB, 0, stream>>>(
        rowptr, csr_src, dinv, (const uint4*)hs2, b2, h2, nullptr, N);

    // edge MLP (MFMA): 4 waves/block, 16 edges * EDGE_ITERS per wave
    const long per_block = 4L * 16 * EDGE_ITERS;  // 1024 edges
    const int eblocks = (int)((E + per_block - 1) / per_block);
    k_edge_mfma<<<eblocks, TPB, 0, stream>>>(src, dst, (const uint4*)h2, eattr,
                                             W3, b3, W4, b4, out, E);
}